// Round 6
// baseline (123.362 us; speedup 1.0000x reference)
//
#include <hip/hip_runtime.h>

// Sizes (fixed):
// x: (8,256,64,64) f32 | w_adj: (18,256,1,1) | b_adj: (18)
// w_off: (18,1,3,3) | b_off: (18) | w_def: (256,256,3,3)
// out: (8,256,64,64) f32
//
// Implicit GEMM: out[cout][pix] = sum_{K=tap*256+c} W[cout][K] * col[K][pix]
// M=256, N=32768, K=2304 -> 38.7 GFLOP -> bf16 MFMA.
// Round 6: XCD-aware block mapping (image n -> XCD n, keeps the 2.1 MB xT
// slab + 1.2 MB wfrag L2-resident per XCD) + register double-buffered
// B-fragments (wfrag prefetch one kstep ahead).
//
// ws layout (bytes):
//   xchan f32 : [0,        2359296)
//   off   f32 : [2359296,  4718592)
//   wfrag bf16: [4718592,  5898240)
//   xT    bf16: [5898240,  22675456)   8n x 4096pix x 256c
// Fallback (ws too small): fp32 path, w_t f32 at [4718592, 7077888).

typedef __attribute__((ext_vector_type(8))) short short8v;
typedef __attribute__((ext_vector_type(4))) float f32x4;

#define NPLANE 4096

__device__ inline unsigned bf16_1(float a) {
    unsigned u = __float_as_uint(a);
    u += 0x7fffu + ((u >> 16) & 1u);
    return u >> 16;
}
__device__ inline unsigned bf16_pair(float a, float b) {
    unsigned ua = __float_as_uint(a); ua += 0x7fffu + ((ua >> 16) & 1u);
    unsigned ub = __float_as_uint(b); ub += 0x7fffu + ((ub >> 16) & 1u);
    return (ua >> 16) | (ub & 0xffff0000u);
}
__device__ inline float bl(unsigned u) { return __uint_as_float(u << 16); }
__device__ inline float bh(unsigned u) { return __uint_as_float(u & 0xffff0000u); }

// ---------------- 1x1 conv: split-K over 8 channel groups ----------------
__global__ __launch_bounds__(256) void k_xchan(const float* __restrict__ x,
                                               const float* __restrict__ w_adj,
                                               const float* __restrict__ b_adj,
                                               float* __restrict__ xchan) {
    __shared__ float wsh[256][18];
    __shared__ float part[8][32][19];
    int t = threadIdx.x;
    for (int i = t; i < 18 * 256; i += 256) {
        int o = i >> 8, c = i & 255;
        wsh[c][o] = w_adj[i];
    }
    __syncthreads();
    int n    = blockIdx.x >> 7;
    int pix0 = (blockIdx.x & 127) << 5;
    int p = t & 31, g = t >> 5;
    const float* xp = x + ((size_t)n << 20) + ((size_t)g << 17) + pix0 + p;
    float acc[18];
#pragma unroll
    for (int o = 0; o < 18; ++o) acc[o] = 0.f;
#pragma unroll 4
    for (int ci = 0; ci < 32; ++ci) {
        float xv = xp[(size_t)ci << 12];
        const float* wr = wsh[(g << 5) + ci];
#pragma unroll
        for (int o = 0; o < 18; ++o) acc[o] = fmaf(xv, wr[o], acc[o]);
    }
#pragma unroll
    for (int o = 0; o < 18; ++o) part[g][p][o] = acc[o];
    __syncthreads();
    for (int i = t; i < 576; i += 256) {
        int o = i >> 5, p2 = i & 31;
        float s = b_adj[o];
#pragma unroll
        for (int g2 = 0; g2 < 8; ++g2) s += part[g2][p2][o];
        xchan[((size_t)n * 18 + o) * NPLANE + pix0 + p2] = s;
    }
}

// ---------------- depthwise 3x3 (groups=18), pad=1 ----------------
__global__ __launch_bounds__(256) void k_off(const float* __restrict__ xchan,
                                             const float* __restrict__ w_off,
                                             const float* __restrict__ b_off,
                                             float* __restrict__ off) {
    int idx = blockIdx.x * 256 + threadIdx.x;
    int pix = idx & 4095;
    int w = pix & 63, h = pix >> 6;
    int rest = idx >> 12;
    int oc = rest % 18;
    const float* wp  = w_off + oc * 9;
    const float* src = xchan + (idx & ~4095);
    float acc = b_off[oc];
#pragma unroll
    for (int i = 0; i < 3; ++i) {
        int hh = h - 1 + i;
        if ((unsigned)hh >= 64u) continue;
#pragma unroll
        for (int j = 0; j < 3; ++j) {
            int ww = w - 1 + j;
            if ((unsigned)ww >= 64u) continue;
            acc = fmaf(src[(hh << 6) + ww], wp[i * 3 + j], acc);
        }
    }
    off[idx] = acc;
}

// ---------------- weight -> MFMA A-fragment layout (bf16) ----------------
// wfrag element idx = ((kstep*16 + ct)*64 + lane)*8 + e
// cout = ct*16 + (lane&15); c = (kstep&7)*32 + (lane>>4)*8 + e; tap = kstep>>3
__global__ __launch_bounds__(256) void k_wfrag(const float* __restrict__ w_def,
                                               ushort* __restrict__ wfrag) {
    int idx = blockIdx.x * 256 + threadIdx.x;   // over 589824
    int e     = idx & 7;
    int lane  = (idx >> 3) & 63;
    int ct    = (idx >> 9) & 15;
    int kstep = idx >> 13;
    int cout = ct * 16 + (lane & 15);
    int c    = ((kstep & 7) << 5) + ((lane >> 4) << 3) + e;
    int tap  = kstep >> 3;
    float v = w_def[cout * 2304 + c * 9 + tap];
    wfrag[idx] = (ushort)bf16_1(v);
}

// ---------------- transpose: x (n,c,pix) f32 -> xT (n,pix,c) bf16 --------
// XCD-aware: n in LOW 3 bits of blockIdx so image n is written by XCD n.
__global__ __launch_bounds__(256) void k_trans(const float* __restrict__ x,
                                               ushort* __restrict__ xT) {
    __shared__ unsigned tileU[64][35];   // [pix][c/2], pad 35 (conflict-free)
    int b  = blockIdx.x;
    int n  = b & 7;
    int cg = (b >> 3) & 3;
    int pg = b >> 5;
    int t  = threadIdx.x;
    int pl = t & 63, c4 = t >> 6;
    const float* src = x + (((size_t)(n * 256 + cg * 64 + c4 * 16)) << 12)
                         + (pg << 6) + pl;
#pragma unroll
    for (int i2 = 0; i2 < 8; ++i2) {
        float f0 = src[(size_t)(2 * i2) << 12];
        float f1 = src[(size_t)(2 * i2 + 1) << 12];
        tileU[pl][c4 * 8 + i2] = bf16_pair(f0, f1);
    }
    __syncthreads();
    int cl2 = t & 31, pr = t >> 5;
    unsigned* dst = (unsigned*)xT;
#pragma unroll
    for (int i = 0; i < 8; ++i) {
        int p2 = pr + (i << 3);
        dst[((size_t)(n << 12) + (pg << 6) + p2) * 128 + (cg << 5) + cl2] =
            tileU[p2][cl2];
    }
}

// ---------------- fused sampler + MFMA GEMM ----------------
// block = 4 waves = 64 px (4 frag tiles) x 256 couts; grid = 512.
// XCD-aware: n = blockIdx & 7 -> all 64 blocks of image n on XCD n
// (xT slab 2.1 MB + wfrag 1.2 MB + off 0.3 MB < 4 MB L2 per XCD).
// Per kstep: gathers for ks+1, wfrag prefetch for ks+1 (reg dbuf),
// LDS A-frags, 16 MFMA, interp+LDS write, 1 barrier.
__global__ __launch_bounds__(256) void k_fused(const ushort* __restrict__ xT,
                                               const float* __restrict__ off,
                                               const ushort* __restrict__ wfrag,
                                               float* __restrict__ out) {
    __shared__ ushort colS[2][4][64][8];   // 8 KB, double-buffered

    int t = threadIdx.x;
    int wv = t >> 6, lane = t & 63;
    int n  = blockIdx.x & 7;
    int tq = blockIdx.x >> 3;

    int plo  = lane & 15;
    int spix = (tq << 6) + (wv << 4) + plo;   // this thread's sample pixel
    int sc   = (lane >> 4) << 3;              // channel offset in 32-group
    int sy = spix >> 6, sx = spix & 63;

    // preload offsets for all 9 taps (compile-time indexed -> registers)
    float oy[9], ox[9];
    const float* offn = off + (((size_t)n * 18) << 12) + spix;
#pragma unroll
    for (int tp = 0; tp < 9; ++tp) {
        oy[tp] = offn[(size_t)(2 * tp) << 12];
        ox[tp] = offn[(size_t)(2 * tp + 1) << 12];
    }

    const ushort* xTn = xT + (((size_t)n) << 12) * 256;

    float w00, w01, w10, w11;
    unsigned oA, oB, oC, oD;    // element offsets into xTn for corner gathers

    auto tap_setup = [&](int tp) {
        float py = (float)(sy - 1 + tp / 3) + oy[tp];
        float px = (float)(sx - 1 + tp % 3) + ox[tp];
        float fy = floorf(py), fx = floorf(px);
        int y0 = (int)fy, x0 = (int)fx;
        float wy1 = py - fy, wx1 = px - fx;
        float ay0 = ((unsigned)y0       < 64u) ? 1.f - wy1 : 0.f;
        float ay1 = ((unsigned)(y0 + 1) < 64u) ? wy1 : 0.f;
        float ax0 = ((unsigned)x0       < 64u) ? 1.f - wx1 : 0.f;
        float ax1 = ((unsigned)(x0 + 1) < 64u) ? wx1 : 0.f;
        w00 = ay0 * ax0; w01 = ay0 * ax1; w10 = ay1 * ax0; w11 = ay1 * ax1;
        int yc0 = min(max(y0, 0), 63), yc1 = min(max(y0 + 1, 0), 63);
        int xc0 = min(max(x0, 0), 63), xc1 = min(max(x0 + 1, 0), 63);
        oA = (unsigned)((((yc0 << 6) + xc0) << 8) + sc);
        oB = (unsigned)((((yc0 << 6) + xc1) << 8) + sc);
        oC = (unsigned)((((yc1 << 6) + xc0) << 8) + sc);
        oD = (unsigned)((((yc1 << 6) + xc1) << 8) + sc);
    };

    auto interp_write = [&](int nb, uint4 A, uint4 B, uint4 C, uint4 D) {
        unsigned qa[4] = {A.x, A.y, A.z, A.w};
        unsigned qb[4] = {B.x, B.y, B.z, B.w};
        unsigned qc[4] = {C.x, C.y, C.z, C.w};
        unsigned qd[4] = {D.x, D.y, D.z, D.w};
        unsigned rr[4];
#pragma unroll
        for (int i = 0; i < 4; ++i) {
            float v0 = w00 * bl(qa[i]) + w01 * bl(qb[i]) +
                       w10 * bl(qc[i]) + w11 * bl(qd[i]);
            float v1 = w00 * bh(qa[i]) + w01 * bh(qb[i]) +
                       w10 * bh(qc[i]) + w11 * bh(qd[i]);
            rr[i] = bf16_pair(v0, v1);
        }
        *(uint4*)&colS[nb][wv][lane][0] = make_uint4(rr[0], rr[1], rr[2], rr[3]);
    };

    f32x4 acc[4][4] = {};

    // prologue: sample kstep 0 into buffer 0; preload B-frags for kstep 0
    tap_setup(0);
    {
        uint4 A = *(const uint4*)(xTn + oA);
        uint4 B = *(const uint4*)(xTn + oB);
        uint4 C = *(const uint4*)(xTn + oC);
        uint4 D = *(const uint4*)(xTn + oD);
        interp_write(0, A, B, C, D);
    }
    short8v bbC[4];
    {
        const ushort* wbk0 = wfrag + (size_t)(wv << 2) * 512 + (lane << 3);
#pragma unroll
        for (int j = 0; j < 4; ++j)
            bbC[j] = *(const short8v*)(wbk0 + (size_t)j * 512);
    }
    __syncthreads();

#pragma unroll
    for (int tap = 0; tap < 9; ++tap) {
#pragma unroll 1
        for (int kc = 0; kc < 8; ++kc) {
            const int ks  = tap * 8 + kc;
            const int cur = ks & 1;
            const bool have = (kc < 7) || (tap < 8);
            // 1. issue gathers for ks+1
            uint4 A = {0,0,0,0}, B = {0,0,0,0}, C = {0,0,0,0}, D = {0,0,0,0};
            if (kc < 7) {
                unsigned d = (unsigned)((kc + 1) << 5);
                A = *(const uint4*)(xTn + oA + d);
                B = *(const uint4*)(xTn + oB + d);
                C = *(const uint4*)(xTn + oC + d);
                D = *(const uint4*)(xTn + oD + d);
            } else if (tap < 8) {
                tap_setup(tap + 1);     // compile-time tap index
                A = *(const uint4*)(xTn + oA);
                B = *(const uint4*)(xTn + oB);
                C = *(const uint4*)(xTn + oC);
                D = *(const uint4*)(xTn + oD);
            }
            // 2. prefetch B-frags for ks+1 (register double-buffer)
            const int ksn = (ks < 71) ? ks + 1 : 71;
            const ushort* wbkN = wfrag + ((size_t)ksn * 16 + (wv << 2)) * 512
                                        + (lane << 3);
            short8v bbN[4];
#pragma unroll
            for (int j = 0; j < 4; ++j)
                bbN[j] = *(const short8v*)(wbkN + (size_t)j * 512);
            // 3. A-fragments from LDS
            short8v a[4];
#pragma unroll
            for (int i = 0; i < 4; ++i)
                a[i] = *(const short8v*)&colS[cur][i][lane][0];
            // 4. MFMA with current B-frags (already in registers)
#pragma unroll
            for (int i = 0; i < 4; ++i)
#pragma unroll
                for (int j = 0; j < 4; ++j)
                    acc[i][j] = __builtin_amdgcn_mfma_f32_16x16x32_bf16(
                        bbC[j], a[i], acc[i][j], 0, 0, 0);
            // 5. interp + LDS write for ks+1
            if (have) interp_write(cur ^ 1, A, B, C, D);
            __syncthreads();
#pragma unroll
            for (int j = 0; j < 4; ++j) bbC[j] = bbN[j];
        }
    }

    // epilogue: D layout col = lane&15 (pix), row = (lane>>4)*4 + r (cout)
    int cl = lane & 15;
    int ch = (lane >> 4) << 2;
    float* outn = out + ((size_t)n << 20);
#pragma unroll
    for (int i = 0; i < 4; ++i) {
        int pix = (tq << 6) + (i << 4) + cl;
#pragma unroll
        for (int j = 0; j < 4; ++j) {
            int cout = (wv << 6) + (j << 4) + ch;
            float* op = outn + ((size_t)cout << 12) + pix;
#pragma unroll
            for (int rr = 0; rr < 4; ++rr) op[(size_t)rr << 12] = acc[i][j][rr];
        }
    }
}

// ================= fallback fp32 path (ws too small) =================
__global__ __launch_bounds__(256) void k_reorder(const float* __restrict__ w_def,
                                                 float* __restrict__ w_t) {
    int idx = blockIdx.x * 256 + threadIdx.x;
    int co = idx & 255;
    int c  = (idx >> 8) & 255;
    int k  = idx >> 16;
    w_t[idx] = w_def[co * 2304 + c * 9 + k];
}

__global__ __launch_bounds__(256) void k_deform(const float* __restrict__ x,
                                                const float* __restrict__ off,
                                                const float* __restrict__ w_t,
                                                float* __restrict__ out) {
    __shared__ float colS[16][64];
    __shared__ float wS[16][128];
    __shared__ int   sy0[64], sx0[64];
    __shared__ float swy[64], swx[64];
    int t   = threadIdx.x;
    int n   = blockIdx.x >> 6;
    int h   = blockIdx.x & 63;
    int co0 = blockIdx.y << 7;
    float acc[4][8];
#pragma unroll
    for (int i = 0; i < 4; ++i)
#pragma unroll
        for (int j = 0; j < 8; ++j) acc[i][j] = 0.f;
    int tp = t & 15, tc = t >> 4;
    int cc_b = t >> 4, p0_b = (t & 15) << 2;
    const float* xn = x + (n << 20);
    for (int k = 0; k < 9; ++k) {
        if (t < 64) {
            const float* offp = off + ((n * 18 + 2 * k) << 12) + (h << 6);
            float oyv = offp[t];
            float oxv = offp[4096 + t];
            float py = (float)(h - 1 + k / 3) + oyv;
            float px = (float)(t - 1 + k % 3) + oxv;
            float fy = floorf(py), fx = floorf(px);
            sy0[t] = (int)fy; sx0[t] = (int)fx;
            swy[t] = py - fy; swx[t] = px - fx;
        }
        for (int c0 = 0; c0 < 256; c0 += 16) {
            __syncthreads();
            const float* base = xn + ((c0 + cc_b) << 12);
#pragma unroll
            for (int u = 0; u < 4; ++u) {
                int p = p0_b + u;
                int y0 = sy0[p], x0 = sx0[p];
                float wy = swy[p], wx = swx[p];
                float v00 = 0.f, v01 = 0.f, v10 = 0.f, v11 = 0.f;
                bool oky0 = (unsigned)y0 < 64u, oky1 = (unsigned)(y0 + 1) < 64u;
                bool okx0 = (unsigned)x0 < 64u, okx1 = (unsigned)(x0 + 1) < 64u;
                int r0 = (y0 << 6) + x0;
                if (oky0 && okx0) v00 = base[r0];
                if (oky0 && okx1) v01 = base[r0 + 1];
                if (oky1 && okx0) v10 = base[r0 + 64];
                if (oky1 && okx1) v11 = base[r0 + 65];
                colS[cc_b][p] = (v00 * (1.f - wx) + v01 * wx) * (1.f - wy) +
                                (v10 * (1.f - wx) + v11 * wx) * wy;
            }
            const float* wt = w_t + (k << 16) + (c0 << 8) + co0;
#pragma unroll
            for (int i = 0; i < 2; ++i) {
                int fi = i * 256 + t;
                int cc = fi >> 5;
                int cf = (fi & 31) << 2;
                *(float4*)&wS[cc][cf] = *(const float4*)&wt[(cc << 8) + cf];
            }
            __syncthreads();
#pragma unroll
            for (int kk = 0; kk < 16; ++kk) {
                float4 cv = *(const float4*)&colS[kk][tp << 2];
                float4 w0 = *(const float4*)&wS[kk][tc << 3];
                float4 w1 = *(const float4*)&wS[kk][(tc << 3) + 4];
                float cva[4] = {cv.x, cv.y, cv.z, cv.w};
                float wa[8]  = {w0.x, w0.y, w0.z, w0.w, w1.x, w1.y, w1.z, w1.w};
#pragma unroll
                for (int i = 0; i < 4; ++i)
#pragma unroll
                    for (int j = 0; j < 8; ++j)
                        acc[i][j] = fmaf(cva[i], wa[j], acc[i][j]);
            }
        }
    }
    int ob = (n << 20) + ((co0 + (tc << 3)) << 12) + (h << 6) + (tp << 2);
#pragma unroll
    for (int j = 0; j < 8; ++j) {
        float4 v = {acc[0][j], acc[1][j], acc[2][j], acc[3][j]};
        *(float4*)&out[ob + (j << 12)] = v;
    }
}

extern "C" void kernel_launch(void* const* d_in, const int* in_sizes, int n_in,
                              void* d_out, int out_size, void* d_ws, size_t ws_size,
                              hipStream_t stream) {
    const float* x     = (const float*)d_in[0];
    const float* w_adj = (const float*)d_in[1];
    const float* b_adj = (const float*)d_in[2];
    const float* w_off = (const float*)d_in[3];
    const float* b_off = (const float*)d_in[4];
    const float* w_def = (const float*)d_in[5];
    float* out = (float*)d_out;

    char* ws = (char*)d_ws;
    float* xchan = (float*)ws;                          // 2359296 B
    float* off   = (float*)(ws + 2359296);              // 2359296 B

    k_xchan<<<1024, 256, 0, stream>>>(x, w_adj, b_adj, xchan);
    k_off<<<2304, 256, 0, stream>>>(xchan, w_off, b_off, off);

    const size_t NEED = 22675456;
    if (ws_size >= NEED) {
        ushort* wfrag = (ushort*)(ws + 4718592);        // 1179648 B
        ushort* xT    = (ushort*)(ws + 5898240);        // 16777216 B
        k_wfrag<<<2304, 256, 0, stream>>>(w_def, wfrag);
        k_trans<<<2048, 256, 0, stream>>>(x, xT);
        k_fused<<<512, 256, 0, stream>>>(xT, off, wfrag, out);
    } else {
        float* w_t = (float*)(ws + 4718592);
        k_reorder<<<2304, 256, 0, stream>>>(w_def, w_t);
        k_deform<<<dim3(512, 2), 256, 0, stream>>>(x, off, w_t, out);
    }
}